// Round 5
// baseline (2743.685 us; speedup 1.0000x reference)
//
#include <hip/hip_runtime.h>
#include <math.h>

#define S_LEN 2048
#define B_SZ 8
#define D_IN 1024
#define DS_ 128
#define INV_TEMP (1.0f/1.000001f)

// Relaxed workgroup barrier: orders LDS ops only (no vmcnt drain) — global
// prefetch loads stay in flight across it.
#define BAR_LDS() asm volatile("s_waitcnt lgkmcnt(0)\n\ts_barrier" ::: "memory")

// DPP row-butterfly sum across the 16-lane row (lanes sharing tid>>4).
#define DPPADD(x, ctrl) { int t_ = __builtin_amdgcn_update_dpp( \
    0, __float_as_int(x), ctrl, 0xF, 0xF, false); x += __int_as_float(t_); }
#define ROWSUM(x) { DPPADD(x, 0x128) DPPADD(x, 0x124) DPPADD(x, 0x122) DPPADD(x, 0x121) }
#define ROWSUM4(v4) { ROWSUM(v4.x) ROWSUM(v4.y) ROWSUM(v4.z) ROWSUM(v4.w) }

// Cross-row butterfly via gfx950 permlane swaps (VALU pipe). Subscript access
// only — macro args must not substitute into member names (round-3 lesson).
typedef unsigned int uint2v __attribute__((ext_vector_type(2)));
#define XSUM16(XV) { uint2v r_ = __builtin_amdgcn_permlane16_swap( \
    __float_as_uint(XV), __float_as_uint(XV), false, false); \
    XV = __uint_as_float(r_[0]) + __uint_as_float(r_[1]); }
#define XSUM32(XV) { uint2v r_ = __builtin_amdgcn_permlane32_swap( \
    __float_as_uint(XV), __float_as_uint(XV), false, false); \
    XV = __uint_as_float(r_[0]) + __uint_as_float(r_[1]); }

// ---------------------------------------------------------------------------
// Kernel 1: fused projection GEMM  P[16384][512] = x @ [Wk|Wv|Wq|Wa]^T
// 128x128 tile, 8x8 acc/thread. N-tile==128 => one W matrix per block.
// ---------------------------------------------------------------------------
__global__ __launch_bounds__(256) void proj_gemm(
    const float* __restrict__ X,
    const float* __restrict__ Wk, const float* __restrict__ Wv,
    const float* __restrict__ Wq, const float* __restrict__ Wa,
    float* __restrict__ P)
{
    __shared__ __align__(16) float As[32][132];
    __shared__ __align__(16) float Bs[32][132];
    const int tid = threadIdx.x;
    const int m0 = blockIdx.x * 128;
    const int n0 = blockIdx.y * 128;
    const int sr = tid >> 3;      // 0..31: row-group for staging
    const int sk = tid & 7;       // 0..7:  k-float4 for staging
    const float* Wbase = (n0 == 0) ? Wk : (n0 == 128) ? Wv : (n0 == 256) ? Wq : Wa;
    const int ty = tid >> 4, tx = tid & 15;

    float acc[8][8];
#pragma unroll
    for (int i = 0; i < 8; i++)
#pragma unroll
        for (int j = 0; j < 8; j++) acc[i][j] = 0.f;

    for (int k0 = 0; k0 < D_IN; k0 += 32) {
#pragma unroll
        for (int i = 0; i < 4; i++) {
            int m = sr + i * 32;
            float4 a4 = *(const float4*)(X + (size_t)(m0 + m) * D_IN + k0 + sk * 4);
            As[sk*4+0][m] = a4.x; As[sk*4+1][m] = a4.y;
            As[sk*4+2][m] = a4.z; As[sk*4+3][m] = a4.w;
            float4 b4 = *(const float4*)(Wbase + (size_t)m * D_IN + k0 + sk * 4);
            Bs[sk*4+0][m] = b4.x; Bs[sk*4+1][m] = b4.y;
            Bs[sk*4+2][m] = b4.z; Bs[sk*4+3][m] = b4.w;
        }
        __syncthreads();
#pragma unroll
        for (int kk = 0; kk < 32; kk++) {
            float4 a0 = *(const float4*)(&As[kk][ty * 8]);
            float4 a1 = *(const float4*)(&As[kk][ty * 8 + 4]);
            float4 b0 = *(const float4*)(&Bs[kk][tx * 8]);
            float4 b1 = *(const float4*)(&Bs[kk][tx * 8 + 4]);
            float a[8] = {a0.x,a0.y,a0.z,a0.w,a1.x,a1.y,a1.z,a1.w};
            float b[8] = {b0.x,b0.y,b0.z,b0.w,b1.x,b1.y,b1.z,b1.w};
#pragma unroll
            for (int i = 0; i < 8; i++)
#pragma unroll
                for (int j = 0; j < 8; j++)
                    acc[i][j] = fmaf(a[i], b[j], acc[i][j]);
        }
        __syncthreads();
    }
#pragma unroll
    for (int i = 0; i < 8; i++) {
        float4 o0; o0.x = acc[i][0]; o0.y = acc[i][1]; o0.z = acc[i][2]; o0.w = acc[i][3];
        float4 o1; o1.x = acc[i][4]; o1.y = acc[i][5]; o1.z = acc[i][6]; o1.w = acc[i][7];
        float* dst = P + (size_t)(m0 + ty * 8 + i) * 512 + n0 + tx * 8;
        *(float4*)(dst) = o0; *(float4*)(dst + 4) = o1;
    }
}

// ---------------------------------------------------------------------------
// Kernel 2: postprocess per token. In-place on P: k<-l2norm(k), q<-l2norm(q),
// r-slot<-alpha. G[tok] = sum_k q_k*(1-alpha_k)*k_k.
// ---------------------------------------------------------------------------
__global__ __launch_bounds__(128) void postproc(
    float* __restrict__ P, float* __restrict__ G,
    const float* __restrict__ bA, const float* __restrict__ lam)
{
    const int tok = blockIdx.x, i = threadIdx.x;
    float* row = P + (size_t)tok * 512;
    float kr = row[i], qr = row[256 + i], rr = row[384 + i];
    float ks = kr * kr, qs = qr * qr;
#pragma unroll
    for (int m = 1; m < 64; m <<= 1) { ks += __shfl_xor(ks, m); qs += __shfl_xor(qs, m); }
    __shared__ float sb[6];
    if ((i & 63) == 0) { sb[(i >> 6) * 2] = ks; sb[(i >> 6) * 2 + 1] = qs; }
    __syncthreads();
    float kinv = 1.0f / fmaxf(sqrtf(sb[0] + sb[2]), 1e-12f);
    float qinv = 1.0f / fmaxf(sqrtf(sb[1] + sb[3]), 1e-12f);
    float kn = kr * kinv, qn = qr * qinv;
    float sr = 1.0f / (1.0f + __expf(-(rr + bA[i])));
    float sl = 1.0f / (1.0f + __expf(-lam[i]));
    float la = logf(sl + 1e-8f);
    float al = __expf(8.0f * sr * la);
    row[i] = kn; row[256 + i] = qn; row[384 + i] = al;
    float gi = qn * (1.0f - al) * kn;
#pragma unroll
    for (int m = 1; m < 64; m <<= 1) gi += __shfl_xor(gi, m);
    if ((i & 63) == 0) sb[4 + (i >> 6)] = gi;
    __syncthreads();
    if (i == 0) G[tok] = sb[4] + sb[5];
}

// ---------------------------------------------------------------------------
// Kernel 3: sequential recurrence — REGISTER-DIRECT staging (no LDS for P).
// 8 blocks x 512 threads. Thread (c=tid&15, vp=tid>>4) owns H[k][v],
// k in [c*8,c*8+8), v in [vp*4,vp*4+4).
// Each thread global-loads its own 28-float P-row slice 2 steps ahead into
// registers (7 dwordx4, vmcnt-tracked -> NOT drained by BAR_LDS, so loads
// span barriers). LDS holds only the 8-float errw exchange. The scalar g
// prefetch (s_load, lgkm-tracked) is issued AFTER the barrier so the
// per-step lgkmcnt(0) never waits on it.
// Rationale: R0-R4 counters show per-SIMD VALU issue ~40%; the old
// global->LDS->reg staging put ~670cyc/step of serialized ds_read_b128 on
// the post-barrier critical path (2-phase pathology). This removes it.
// ---------------------------------------------------------------------------
__global__ __launch_bounds__(512, 2) void recurrence(
    const float* __restrict__ P, const float* __restrict__ G, float* __restrict__ Y)
{
    const int b = blockIdx.x;
    const int tid = threadIdx.x;
    const int c = tid & 15;
    const int vp = tid >> 4;      // 0..31
    const int wave = tid >> 6;    // 0..7
    const int ko = c * 8;         // k/q/a slice offset in P row
    const int vo = 128 + vp * 4;  // v slice offset in P row

    __shared__ __align__(16) float errw[2][8];

    const float* Pb = P + (size_t)b * S_LEN * 512;
    const float* Gb = G + (size_t)b * S_LEN;
    float* Yb = Y + (size_t)b * S_LEN * DS_;

    float4 H0={0,0,0,0},H1={0,0,0,0},H2={0,0,0,0},H3={0,0,0,0},
           H4={0,0,0,0},H5={0,0,0,0},H6={0,0,0,0},H7={0,0,0,0};

    // 2-deep register prefetch: set A = even steps, set B = odd steps.
    float4 kA0,kA1,qA0,qA1,aA0,aA1,vA; float gA;
    float4 kB0,kB1,qB0,qB1,aB0,aB1,vB; float gB;
    {
        const float* p0 = Pb;
        kA0 = *(const float4*)(p0 + ko);       kA1 = *(const float4*)(p0 + ko + 4);
        qA0 = *(const float4*)(p0 + 256 + ko); qA1 = *(const float4*)(p0 + 256 + ko + 4);
        aA0 = *(const float4*)(p0 + 384 + ko); aA1 = *(const float4*)(p0 + 384 + ko + 4);
        vA  = *(const float4*)(p0 + vo);       gA  = Gb[0];
        const float* p1 = Pb + 512;
        kB0 = *(const float4*)(p1 + ko);       kB1 = *(const float4*)(p1 + ko + 4);
        qB0 = *(const float4*)(p1 + 256 + ko); qB1 = *(const float4*)(p1 + 256 + ko + 4);
        aB0 = *(const float4*)(p1 + 384 + ko); aB1 = *(const float4*)(p1 + 384 + ko + 4);
        vB  = *(const float4*)(p1 + vo);       gB  = Gb[1];
    }

#define DOTJ(qs, ks, zs, Hj) { \
    pr.x = fmaf(qs, Hj.x, pr.x); pr.y = fmaf(qs, Hj.y, pr.y); \
    pr.z = fmaf(qs, Hj.z, pr.z); pr.w = fmaf(qs, Hj.w, pr.w); \
    kp.x = fmaf(ks, Hj.x, kp.x); kp.y = fmaf(ks, Hj.y, kp.y); \
    kp.z = fmaf(ks, Hj.z, kp.z); kp.w = fmaf(ks, Hj.w, kp.w); \
    ya.x = fmaf(zs, Hj.x, ya.x); ya.y = fmaf(zs, Hj.y, ya.y); \
    ya.z = fmaf(zs, Hj.z, ya.z); ya.w = fmaf(zs, Hj.w, ya.w); }

#define UPDJ(as_, ws_, Hj) { \
    Hj.x = fmaf(as_, Hj.x, ws_ * sd.x); Hj.y = fmaf(as_, Hj.y, ws_ * sd.y); \
    Hj.z = fmaf(as_, Hj.z, ws_ * sd.z); Hj.w = fmaf(as_, Hj.w, ws_ * sd.w); }

// STEP: K0..VT,GS are the per-parity register-set variable names.
// k/q/v regs die after the dot phase -> reload (T+2) issued pre-barrier.
// a regs live through UPDJ -> reloaded after UPDJ. g saved to gcur, its
// (scalar) reload issued after the barrier to keep it off this step's
// lgkmcnt(0). Compiler enforces all RAW/WAR ordering + inserts vmcnt waits.
#define STEP(T, PAR, K0,K1,Q0,Q1,A0,A1,VT,GS) { \
    float4 z0, z1, w0, w1; \
    z0.x = Q0.x * A0.x; z0.y = Q0.y * A0.y; z0.z = Q0.z * A0.z; z0.w = Q0.w * A0.w; \
    z1.x = Q1.x * A1.x; z1.y = Q1.y * A1.y; z1.z = Q1.z * A1.z; z1.w = Q1.w * A1.w; \
    w0.x = fmaf(-K0.x, A0.x, K0.x); w0.y = fmaf(-K0.y, A0.y, K0.y); \
    w0.z = fmaf(-K0.z, A0.z, K0.z); w0.w = fmaf(-K0.w, A0.w, K0.w); \
    w1.x = fmaf(-K1.x, A1.x, K1.x); w1.y = fmaf(-K1.y, A1.y, K1.y); \
    w1.z = fmaf(-K1.z, A1.z, K1.z); w1.w = fmaf(-K1.w, A1.w, K1.w); \
    float4 pr = {0,0,0,0}, kp = {0,0,0,0}, ya = {0,0,0,0}; \
    DOTJ(Q0.x, K0.x, z0.x, H0) DOTJ(Q0.y, K0.y, z0.y, H1) \
    DOTJ(Q0.z, K0.z, z0.z, H2) DOTJ(Q0.w, K0.w, z0.w, H3) \
    DOTJ(Q1.x, K1.x, z1.x, H4) DOTJ(Q1.y, K1.y, z1.y, H5) \
    DOTJ(Q1.z, K1.z, z1.z, H6) DOTJ(Q1.w, K1.w, z1.w, H7) \
    ROWSUM4(pr) ROWSUM4(kp) ROWSUM4(ya) \
    float4 d4; d4.x = VT.x - kp.x; d4.y = VT.y - kp.y; \
    d4.z = VT.z - kp.z; d4.w = VT.w - kp.w; \
    float ex = VT.x - pr.x, ey = VT.y - pr.y, ez = VT.z - pr.z, ew = VT.w - pr.w; \
    float ep = fmaf(ex, ex, fmaf(ey, ey, fmaf(ez, ez, ew * ew))); \
    XSUM16(ep) XSUM32(ep) \
    if ((tid & 63) == 0) errw[PAR][wave] = ep; \
    const float gcur = GS; \
    if ((T) + 2 < S_LEN) { \
        const float* ps_ = Pb + (size_t)((T) + 2) * 512; \
        K0 = *(const float4*)(ps_ + ko);       K1 = *(const float4*)(ps_ + ko + 4); \
        Q0 = *(const float4*)(ps_ + 256 + ko); Q1 = *(const float4*)(ps_ + 256 + ko + 4); \
        VT = *(const float4*)(ps_ + vo); } \
    BAR_LDS(); \
    const float4 ea = *(const float4*)(&errw[PAR][0]); \
    const float4 eb = *(const float4*)(&errw[PAR][4]); \
    float err = ((ea.x + ea.y) + (ea.z + ea.w)) + ((eb.x + eb.y) + (eb.z + eb.w)); \
    float sur = 1.0f / (1.0f + __expf(-err * INV_TEMP)); \
    float4 sd; sd.x = sur * d4.x; sd.y = sur * d4.y; \
    sd.z = sur * d4.z; sd.w = sur * d4.w; \
    if (c == 0) { \
        float sg = sur * gcur; float4 y4; \
        y4.x = fmaf(sg, d4.x, ya.x); y4.y = fmaf(sg, d4.y, ya.y); \
        y4.z = fmaf(sg, d4.z, ya.z); y4.w = fmaf(sg, d4.w, ya.w); \
        *(float4*)(Yb + (size_t)(T) * DS_ + vp * 4) = y4; } \
    if ((T) + 2 < S_LEN) GS = Gb[(T) + 2]; \
    UPDJ(A0.x, w0.x, H0) UPDJ(A0.y, w0.y, H1) \
    UPDJ(A0.z, w0.z, H2) UPDJ(A0.w, w0.w, H3) \
    UPDJ(A1.x, w1.x, H4) UPDJ(A1.y, w1.y, H5) \
    UPDJ(A1.z, w1.z, H6) UPDJ(A1.w, w1.w, H7) \
    if ((T) + 2 < S_LEN) { \
        const float* ps_ = Pb + (size_t)((T) + 2) * 512; \
        A0 = *(const float4*)(ps_ + 384 + ko); A1 = *(const float4*)(ps_ + 384 + ko + 4); } \
}

    for (int t = 0; t < S_LEN; t += 2) {
        STEP(t,     0, kA0,kA1,qA0,qA1,aA0,aA1,vA,gA)
        STEP(t + 1, 1, kB0,kB1,qB0,qB1,aB0,aB1,vB,gB)
    }
#undef DOTJ
#undef UPDJ
#undef STEP
}

// ---------------------------------------------------------------------------
// Kernel 4: RMSNorm over DS per token (in-place on Y)
// ---------------------------------------------------------------------------
__global__ __launch_bounds__(128) void rmsnorm(
    float* __restrict__ Y, const float* __restrict__ nw)
{
    const int tok = blockIdx.x, i = threadIdx.x;
    float y = Y[(size_t)tok * DS_ + i];
    float s = y * y;
#pragma unroll
    for (int m = 1; m < 64; m <<= 1) s += __shfl_xor(s, m);
    __shared__ float sb[2];
    if ((i & 63) == 0) sb[i >> 6] = s;
    __syncthreads();
    float ms = (sb[0] + sb[1]) * (1.0f / 128.0f);
    Y[(size_t)tok * DS_ + i] = y * rsqrtf(ms + 1e-6f) * nw[i];
}

// ---------------------------------------------------------------------------
// Kernel 5: output GEMM  Out[16384][1024] = Yn[16384][128] @ Wo[1024][128]^T
// 128x128 tile, 8x8 acc/thread.
// ---------------------------------------------------------------------------
__global__ __launch_bounds__(256) void out_gemm(
    const float* __restrict__ Yn, const float* __restrict__ Wo, float* __restrict__ Out)
{
    __shared__ __align__(16) float As[32][132];
    __shared__ __align__(16) float Bs[32][132];
    const int tid = threadIdx.x;
    const int m0 = blockIdx.x * 128;
    const int n0 = blockIdx.y * 128;
    const int sr = tid >> 3;
    const int sk = tid & 7;
    const int ty = tid >> 4, tx = tid & 15;

    float acc[8][8];
#pragma unroll
    for (int i = 0; i < 8; i++)
#pragma unroll
        for (int j = 0; j < 8; j++) acc[i][j] = 0.f;

    for (int k0 = 0; k0 < DS_; k0 += 32) {
#pragma unroll
        for (int i = 0; i < 4; i++) {
            int m = sr + i * 32;
            float4 a4 = *(const float4*)(Yn + (size_t)(m0 + m) * DS_ + k0 + sk * 4);
            As[sk*4+0][m] = a4.x; As[sk*4+1][m] = a4.y;
            As[sk*4+2][m] = a4.z; As[sk*4+3][m] = a4.w;
            float4 b4 = *(const float4*)(Wo + (size_t)(n0 + m) * DS_ + k0 + sk * 4);
            Bs[sk*4+0][m] = b4.x; Bs[sk*4+1][m] = b4.y;
            Bs[sk*4+2][m] = b4.z; Bs[sk*4+3][m] = b4.w;
        }
        __syncthreads();
#pragma unroll
        for (int kk = 0; kk < 32; kk++) {
            float4 a0 = *(const float4*)(&As[kk][ty * 8]);
            float4 a1 = *(const float4*)(&As[kk][ty * 8 + 4]);
            float4 b0 = *(const float4*)(&Bs[kk][tx * 8]);
            float4 b1 = *(const float4*)(&Bs[kk][tx * 8 + 4]);
            float a[8] = {a0.x,a0.y,a0.z,a0.w,a1.x,a1.y,a1.z,a1.w};
            float b[8] = {b0.x,b0.y,b0.z,b0.w,b1.x,b1.y,b1.z,b1.w};
#pragma unroll
            for (int i = 0; i < 8; i++)
#pragma unroll
                for (int j = 0; j < 8; j++)
                    acc[i][j] = fmaf(a[i], b[j], acc[i][j]);
        }
        __syncthreads();
    }
#pragma unroll
    for (int i = 0; i < 8; i++) {
        float4 o0; o0.x = acc[i][0]; o0.y = acc[i][1]; o0.z = acc[i][2]; o0.w = acc[i][3];
        float4 o1; o1.x = acc[i][4]; o1.y = acc[i][5]; o1.z = acc[i][6]; o1.w = acc[i][7];
        float* dst = Out + (size_t)(m0 + ty * 8 + i) * 1024 + n0 + tx * 8;
        *(float4*)(dst) = o0; *(float4*)(dst + 4) = o1;
    }
}

// ---------------------------------------------------------------------------
extern "C" void kernel_launch(void* const* d_in, const int* in_sizes, int n_in,
                              void* d_out, int out_size, void* d_ws, size_t ws_size,
                              hipStream_t stream)
{
    const float* x   = (const float*)d_in[0];
    const float* Wk  = (const float*)d_in[1];
    const float* Wv  = (const float*)d_in[2];
    const float* Wq  = (const float*)d_in[3];
    const float* Waw = (const float*)d_in[4];
    const float* Wab = (const float*)d_in[5];
    const float* lam = (const float*)d_in[6];
    const float* Wo  = (const float*)d_in[7];
    const float* nw  = (const float*)d_in[8];
    float* out = (float*)d_out;

    const size_t NTOK = (size_t)B_SZ * S_LEN;   // 16384
    float* P  = (float*)d_ws;                    // NTOK*512
    float* G  = P + NTOK * 512;                  // NTOK
    float* Y  = G + NTOK;                        // NTOK*128

    proj_gemm<<<dim3(NTOK / 128, 512 / 128), 256, 0, stream>>>(x, Wk, Wv, Wq, Waw, P);
    postproc<<<NTOK, 128, 0, stream>>>(P, G, Wab, lam);
    recurrence<<<B_SZ, 512, 0, stream>>>(P, G, Y);
    rmsnorm<<<NTOK, 128, 0, stream>>>(Y, nw);
    out_gemm<<<dim3(NTOK / 128, 1024 / 128), 256, 0, stream>>>(Y, Wo, out);
}